// Round 1
// baseline (29.237 us; speedup 1.0000x reference)
//
#include <hip/hip_runtime.h>
#include <hip/hip_bf16.h>

#define BB 64
#define KK 128
#define DD 128
#define HH 64

// ---------------------------------------------------------------------------
// Phase 1: L[b][k][h] = b1[h] + slots[b,k,:] . W1[h, 0:128]
//          R[b][k][h] =          slots[b,k,:] . W1[h, 128:256]
// grid = BB * 2(k-tile of 64) * 2(ht: 0=L, 1=R), block = 256 threads.
// LDS: slots tile [64][64+pad] and W1 half-rows [64][64+pad], d split in 2
// passes of 64 to keep LDS ~35KB. 4k x 4h register tile per thread.
// Bank math: pad 68 -> bank contribution of row is 4*row mod 32:
//   slots reads vary over ty(0..3 per wave)  -> banks {0,4,8,12}, conflict-free
//   W1 reads vary over tx(0..15 per wave)    -> 2-way (free on CDNA4)
// ---------------------------------------------------------------------------
__global__ __launch_bounds__(256) void lr_kernel(
    const float* __restrict__ slots, const float* __restrict__ W1,
    const float* __restrict__ b1, float* __restrict__ Lg, float* __restrict__ Rg)
{
    const int blk = blockIdx.x;
    const int b  = blk >> 2;
    const int kt = (blk >> 1) & 1;   // which 64-row k tile
    const int ht = blk & 1;          // 0 -> L (cols 0:128), 1 -> R (cols 128:256)

    __shared__ float S [64 * 68];    // slots[k][d-half]
    __shared__ float Ws[64 * 68];    // W1[h][d-half]

    const int t  = threadIdx.x;
    const int tx = t & 15;           // h' = tx + 16*hh
    const int ty = t >> 4;           // k  = ty + 16*kk

    float acc[4][4];
#pragma unroll
    for (int hh = 0; hh < 4; ++hh) {
        const float binit = (ht == 0) ? b1[tx + 16 * hh] : 0.0f;
#pragma unroll
        for (int kk = 0; kk < 4; ++kk) acc[kk][hh] = binit;
    }

    const float* sp = slots + (size_t)(b * KK + kt * 64) * DD;

    for (int half = 0; half < 2; ++half) {
        // stage slots tile: 64 rows x 64 cols
        for (int x = t; x < 1024; x += 256) {
            const int fi = x * 4;
            const int k = fi >> 6, d = fi & 63;
            float4 v = *reinterpret_cast<const float4*>(sp + k * DD + half * 64 + d);
            *reinterpret_cast<float4*>(&S[k * 68 + d]) = v;
        }
        // stage W1 half: rows 0..63, cols ht*128 + half*64 ..+64
        for (int x = t; x < 1024; x += 256) {
            const int fi = x * 4;
            const int hl = fi >> 6, d = fi & 63;
            float4 v = *reinterpret_cast<const float4*>(W1 + hl * 256 + ht * 128 + half * 64 + d);
            *reinterpret_cast<float4*>(&Ws[hl * 68 + d]) = v;
        }
        __syncthreads();

        const float* Sp = S  + ty * 68;
        const float* Wp = Ws + tx * 68;
#pragma unroll
        for (int d = 0; d < 64; d += 4) {
            float4 a[4], w[4];
#pragma unroll
            for (int kk = 0; kk < 4; ++kk)
                a[kk] = *reinterpret_cast<const float4*>(Sp + kk * (16 * 68) + d);
#pragma unroll
            for (int hh = 0; hh < 4; ++hh)
                w[hh] = *reinterpret_cast<const float4*>(Wp + hh * (16 * 68) + d);
#pragma unroll
            for (int kk = 0; kk < 4; ++kk)
#pragma unroll
                for (int hh = 0; hh < 4; ++hh) {
                    float s = acc[kk][hh];
                    s = fmaf(a[kk].x, w[hh].x, s);
                    s = fmaf(a[kk].y, w[hh].y, s);
                    s = fmaf(a[kk].z, w[hh].z, s);
                    s = fmaf(a[kk].w, w[hh].w, s);
                    acc[kk][hh] = s;
                }
        }
        __syncthreads();
    }

    float* outp = (ht == 0) ? Lg : Rg;
#pragma unroll
    for (int kk = 0; kk < 4; ++kk) {
        const int k = kt * 64 + ty + 16 * kk;
        float* row = outp + (size_t)(b * KK + k) * HH;
#pragma unroll
        for (int hh = 0; hh < 4; ++hh)
            row[tx + 16 * hh] = acc[kk][hh];
    }
}

// ---------------------------------------------------------------------------
// Phase 2: out[b,i,j] = (i==j) ? 0 : sigmoid(b2 + sum_h relu(L[b,i,h]+R[b,j,h])*W2[h])
// grid = BB * 4(i-tile of 32) * 2(j-tile of 64), block = 128 threads (2 waves).
// 4i x 4j register tile; L reads are 4-address broadcasts (banks {0,4,8,12}),
// R reads are 2-way (free). W2 reads are wave-uniform -> s_load.
// ---------------------------------------------------------------------------
__global__ __launch_bounds__(128) void edge_kernel(
    const float* __restrict__ Lg, const float* __restrict__ Rg,
    const float* __restrict__ W2, const float* __restrict__ b2p,
    float* __restrict__ out)
{
    const int blk = blockIdx.x;
    const int b  = blk >> 3;
    const int it = (blk >> 1) & 3;   // i tile of 32
    const int jt = blk & 1;          // j tile of 64

    __shared__ float Ls[32 * 68];
    __shared__ float Rs[64 * 68];

    const int t = threadIdx.x;

    const float* lp = Lg + (size_t)(b * KK + it * 32) * HH;
    for (int x = t; x < 512; x += 128) {
        const int fi = x * 4;
        const int r = fi >> 6, h = fi & 63;
        *reinterpret_cast<float4*>(&Ls[r * 68 + h]) =
            *reinterpret_cast<const float4*>(lp + fi);
    }
    const float* rp = Rg + (size_t)(b * KK + jt * 64) * HH;
    for (int x = t; x < 1024; x += 128) {
        const int fi = x * 4;
        const int r = fi >> 6, h = fi & 63;
        *reinterpret_cast<float4*>(&Rs[r * 68 + h]) =
            *reinterpret_cast<const float4*>(rp + fi);
    }
    __syncthreads();

    const int tx = t & 15;          // j = tx + 16*jj
    const int ty = t >> 4;          // i = ty + 8*ii   (ty 0..7)

    float acc[4][4] = {};
    const float* Lp = Ls + ty * 68;
    const float* Rp = Rs + tx * 68;

#pragma unroll
    for (int h = 0; h < 64; h += 4) {
        const float4 w4 = *reinterpret_cast<const float4*>(W2 + h);
        float4 l4[4], r4[4];
#pragma unroll
        for (int ii = 0; ii < 4; ++ii)
            l4[ii] = *reinterpret_cast<const float4*>(Lp + ii * (8 * 68) + h);
#pragma unroll
        for (int jj = 0; jj < 4; ++jj)
            r4[jj] = *reinterpret_cast<const float4*>(Rp + jj * (16 * 68) + h);
#pragma unroll
        for (int ii = 0; ii < 4; ++ii)
#pragma unroll
            for (int jj = 0; jj < 4; ++jj) {
                float s;
                s = fmaxf(l4[ii].x + r4[jj].x, 0.0f); acc[ii][jj] = fmaf(s, w4.x, acc[ii][jj]);
                s = fmaxf(l4[ii].y + r4[jj].y, 0.0f); acc[ii][jj] = fmaf(s, w4.y, acc[ii][jj]);
                s = fmaxf(l4[ii].z + r4[jj].z, 0.0f); acc[ii][jj] = fmaf(s, w4.z, acc[ii][jj]);
                s = fmaxf(l4[ii].w + r4[jj].w, 0.0f); acc[ii][jj] = fmaf(s, w4.w, acc[ii][jj]);
            }
    }

    const float b2 = *b2p;
#pragma unroll
    for (int ii = 0; ii < 4; ++ii) {
        const int gi = it * 32 + ty + 8 * ii;
        float* orow = out + (size_t)(b * KK + gi) * KK + jt * 64;
#pragma unroll
        for (int jj = 0; jj < 4; ++jj) {
            const int jl = tx + 16 * jj;
            const int gj = jt * 64 + jl;
            const float x = acc[ii][jj] + b2;
            const float sig = 1.0f / (1.0f + __expf(-x));
            orow[jl] = (gi == gj) ? 0.0f : sig;
        }
    }
}

// ---------------------------------------------------------------------------
// Correctness-only fallback if the workspace is too small (no scratch needed).
// grid = BB*KK blocks (one (b,i) row), 128 threads (thread = j).
// ---------------------------------------------------------------------------
__global__ __launch_bounds__(128) void fused_fallback(
    const float* __restrict__ slots, const float* __restrict__ W1,
    const float* __restrict__ b1, const float* __restrict__ W2,
    const float* __restrict__ b2p, float* __restrict__ out)
{
    const int blk = blockIdx.x;
    const int b = blk >> 7, i = blk & 127;
    __shared__ float Li[64];
    const int t = threadIdx.x;

    if (t < 64) {
        float a = b1[t];
        const float* srow = slots + (size_t)(b * KK + i) * DD;
        const float* w = W1 + t * 256;
        for (int d = 0; d < DD; ++d) a = fmaf(srow[d], w[d], a);
        Li[t] = a;
    }
    __syncthreads();

    const float* srow = slots + (size_t)(b * KK + t) * DD;  // thread t = j
    float acc = *b2p;
    for (int h = 0; h < HH; ++h) {
        const float* w = W1 + h * 256 + 128;
        float r = 0.0f;
        for (int d = 0; d < DD; ++d) r = fmaf(srow[d], w[d], r);
        const float s = fmaxf(Li[h] + r, 0.0f);
        acc = fmaf(s, W2[h], acc);
    }
    const float sig = 1.0f / (1.0f + __expf(-acc));
    out[(size_t)(b * KK + i) * KK + t] = (i == t) ? 0.0f : sig;
}

extern "C" void kernel_launch(void* const* d_in, const int* in_sizes, int n_in,
                              void* d_out, int out_size, void* d_ws, size_t ws_size,
                              hipStream_t stream) {
    const float* slots = (const float*)d_in[0];
    const float* W1    = (const float*)d_in[1];
    const float* b1    = (const float*)d_in[2];
    const float* W2    = (const float*)d_in[3];
    const float* b2    = (const float*)d_in[4];
    float* out = (float*)d_out;

    const size_t need = (size_t)2 * BB * KK * HH * sizeof(float);  // 4 MB for L,R
    if (ws_size >= need) {
        float* Lg = (float*)d_ws;
        float* Rg = Lg + (size_t)BB * KK * HH;
        lr_kernel  <<<BB * 4, 256, 0, stream>>>(slots, W1, b1, Lg, Rg);
        edge_kernel<<<BB * 8, 128, 0, stream>>>(Lg, Rg, W2, b2, out);
    } else {
        fused_fallback<<<BB * KK, 128, 0, stream>>>(slots, W1, b1, W2, b2, out);
    }
}

// Round 2
// 16.117 us; speedup vs baseline: 1.8140x; 1.8140x over previous
//
#include <hip/hip_runtime.h>

#define BB 64
#define KK 128
#define DD 128
#define HH 64

typedef __attribute__((ext_vector_type(8))) short bf16x8;
typedef __attribute__((ext_vector_type(4))) float f32x4;

// round-to-nearest-even fp32 -> bf16, packed pair (lo = x, hi = y)
__device__ __forceinline__ unsigned f2bf2(float x, float y) {
    unsigned xu = __float_as_uint(x), yu = __float_as_uint(y);
    xu += 0x7fffu + ((xu >> 16) & 1u);
    yu += 0x7fffu + ((yu >> 16) & 1u);
    return (xu >> 16) | (yu & 0xffff0000u);
}

// LDS map (64 KiB union, barrier-separated):
//  phase A: SA  bf16[128][128] at 0      (rows 0-63: slots[i-tile], 64-127: slots[j-tile])
//           W1s bf16[64][256]  at 32768
//           both XOR-swizzled per 16B block: blk' = blk ^ (row & 7)  -> uniform banks
//  phase B: Ls f32[64][68] at 0, Rs f32[64][68] at 17408, W2s f32[64] at 34816
__global__ __launch_bounds__(256) void fused_kernel(
    const float* __restrict__ slots, const float* __restrict__ W1,
    const float* __restrict__ b1, const float* __restrict__ W2,
    const float* __restrict__ b2p, float* __restrict__ out)
{
    __shared__ uint4 smem_u4[4096];          // 65536 B
    char* smem = (char*)smem_u4;

    const int t   = threadIdx.x;
    const int blk = blockIdx.x;
    const int b   = blk >> 2;
    const int it  = (blk >> 1) & 1;          // i half (64 rows)
    const int jt  = blk & 1;                 // j half (64 rows)

    // b1 values for this lane's h-columns (h = nt*16 + (t&15))
    float b1v[4];
#pragma unroll
    for (int nt = 0; nt < 4; ++nt) b1v[nt] = b1[nt * 16 + (t & 15)];

    // ---------------- stage SA + W1 as swizzled bf16 ----------------
    {
        const float* srcI = slots + ((size_t)(b * KK) + it * 64) * DD;
        const float* srcJ = slots + ((size_t)(b * KK) + jt * 64) * DD;
#pragma unroll
        for (int x0 = 0; x0 < 2048; x0 += 256) {           // 128 rows x 16 8-col blocks
            const int x = x0 + t;
            const int row = x >> 4, cb = x & 15;
            const float* src = (row < 64 ? srcI + row * DD
                                         : srcJ + (row - 64) * DD) + cb * 8;
            const float4 f0 = *reinterpret_cast<const float4*>(src);
            const float4 f1 = *reinterpret_cast<const float4*>(src + 4);
            uint4 pk;
            pk.x = f2bf2(f0.x, f0.y); pk.y = f2bf2(f0.z, f0.w);
            pk.z = f2bf2(f1.x, f1.y); pk.w = f2bf2(f1.z, f1.w);
            *reinterpret_cast<uint4*>(smem + row * 256 + ((cb ^ (row & 7)) << 4)) = pk;
        }
#pragma unroll
        for (int x0 = 0; x0 < 2048; x0 += 256) {           // 64 rows x 32 8-col blocks
            const int x = x0 + t;
            const int row = x >> 5, cb = x & 31;
            const float* src = W1 + row * 256 + cb * 8;
            const float4 f0 = *reinterpret_cast<const float4*>(src);
            const float4 f1 = *reinterpret_cast<const float4*>(src + 4);
            uint4 pk;
            pk.x = f2bf2(f0.x, f0.y); pk.y = f2bf2(f0.z, f0.w);
            pk.z = f2bf2(f1.x, f1.y); pk.w = f2bf2(f1.z, f1.w);
            *reinterpret_cast<uint4*>(smem + 32768 + row * 512 + ((cb ^ (row & 7)) << 4)) = pk;
        }
    }
    __syncthreads();

    // ---------------- MFMA: L = S_i . W1L^T (+b1 later), R = S_j . W1R^T ----------
    const int lane = t & 63;
    const int w    = t >> 6;                 // wave id: m-tile
    const int lr   = lane & 15;
    const int lk   = lane >> 4;              // 0..3

    f32x4 accL[4], accR[4];
#pragma unroll
    for (int nt = 0; nt < 4; ++nt) {
        accL[nt] = f32x4{0.f, 0.f, 0.f, 0.f};
        accR[nt] = f32x4{0.f, 0.f, 0.f, 0.f};
    }

    bf16x8 aL[4], aR[4];
#pragma unroll
    for (int kf = 0; kf < 4; ++kf) {
        const int c = kf * 4 + lk;
        const int rowL = 16 * w + lr;
        aL[kf] = *reinterpret_cast<const bf16x8*>(smem + rowL * 256 + ((c ^ (rowL & 7)) << 4));
        const int rowR = 64 + 16 * w + lr;
        aR[kf] = *reinterpret_cast<const bf16x8*>(smem + rowR * 256 + ((c ^ (rowR & 7)) << 4));
    }
#pragma unroll
    for (int nt = 0; nt < 4; ++nt) {
        const int rowB = nt * 16 + lr;
#pragma unroll
        for (int kf = 0; kf < 4; ++kf) {
            const int cL = kf * 4 + lk;                    // W1 cols 0..127  (left half)
            bf16x8 bL = *reinterpret_cast<const bf16x8*>(
                smem + 32768 + rowB * 512 + ((cL ^ (rowB & 7)) << 4));
            accL[nt] = __builtin_amdgcn_mfma_f32_16x16x32_bf16(aL[kf], bL, accL[nt], 0, 0, 0);
            const int cR = 16 + kf * 4 + lk;               // W1 cols 128..255 (right half)
            bf16x8 bR = *reinterpret_cast<const bf16x8*>(
                smem + 32768 + rowB * 512 + ((cR ^ (rowB & 7)) << 4));
            accR[nt] = __builtin_amdgcn_mfma_f32_16x16x32_bf16(aR[kf], bR, accR[nt], 0, 0, 0);
        }
    }
    __syncthreads();

    // ---------------- spill L,R (fp32, padded) + W2 into LDS ----------------
    float* Lsp = (float*)smem;                      // [64][68]
    float* Rsp = (float*)(smem + 17408);            // [64][68]
    float* W2s = (float*)(smem + 34816);            // [64]
    if (t < 64) W2s[t] = W2[t];
#pragma unroll
    for (int nt = 0; nt < 4; ++nt) {
        const int h = nt * 16 + lr;
#pragma unroll
        for (int r = 0; r < 4; ++r) {
            const int row = 16 * w + 4 * lk + r;    // D: row = 4*(lane>>4)+reg
            Lsp[row * 68 + h] = accL[nt][r] + b1v[nt];
            Rsp[row * 68 + h] = accR[nt][r];
        }
    }
    __syncthreads();

    // ---------------- pairwise: out[i][j] = sigmoid(b2 + sum_h relu(L+R)*W2) ------
    const int tx = t & 15;                  // j = tx + 16*jj
    const int ty = t >> 4;                  // i = ty + 16*ii  (ty 0..15)

    float acc[4][4] = {};
#pragma unroll
    for (int hs = 0; hs < 16; ++hs) {
        const float4 w4 = *reinterpret_cast<const float4*>(W2s + hs * 4);
        float4 l4[4], r4[4];
#pragma unroll
        for (int ii = 0; ii < 4; ++ii)
            l4[ii] = *reinterpret_cast<const float4*>(Lsp + (ty + 16 * ii) * 68 + hs * 4);
#pragma unroll
        for (int jj = 0; jj < 4; ++jj)
            r4[jj] = *reinterpret_cast<const float4*>(Rsp + (tx + 16 * jj) * 68 + hs * 4);
#pragma unroll
        for (int ii = 0; ii < 4; ++ii)
#pragma unroll
            for (int jj = 0; jj < 4; ++jj) {
                float s;
                s = fmaxf(l4[ii].x + r4[jj].x, 0.0f); acc[ii][jj] = fmaf(s, w4.x, acc[ii][jj]);
                s = fmaxf(l4[ii].y + r4[jj].y, 0.0f); acc[ii][jj] = fmaf(s, w4.y, acc[ii][jj]);
                s = fmaxf(l4[ii].z + r4[jj].z, 0.0f); acc[ii][jj] = fmaf(s, w4.z, acc[ii][jj]);
                s = fmaxf(l4[ii].w + r4[jj].w, 0.0f); acc[ii][jj] = fmaf(s, w4.w, acc[ii][jj]);
            }
    }

    const float b2 = *b2p;
#pragma unroll
    for (int ii = 0; ii < 4; ++ii) {
        const int gi = it * 64 + ty + 16 * ii;
        float* orow = out + ((size_t)(b * KK) + gi) * KK + jt * 64;
#pragma unroll
        for (int jj = 0; jj < 4; ++jj) {
            const int jl = tx + 16 * jj;
            const int gj = jt * 64 + jl;
            const float xv = acc[ii][jj] + b2;
            const float sg = 1.0f / (1.0f + __expf(-xv));
            orow[jl] = (gi == gj) ? 0.0f : sg;
        }
    }
}

extern "C" void kernel_launch(void* const* d_in, const int* in_sizes, int n_in,
                              void* d_out, int out_size, void* d_ws, size_t ws_size,
                              hipStream_t stream) {
    const float* slots = (const float*)d_in[0];
    const float* W1    = (const float*)d_in[1];
    const float* b1    = (const float*)d_in[2];
    const float* W2    = (const float*)d_in[3];
    const float* b2    = (const float*)d_in[4];
    float* out = (float*)d_out;
    (void)d_ws; (void)ws_size;

    fused_kernel<<<BB * 4, 256, 0, stream>>>(slots, W1, b1, W2, b2, out);
}

// Round 4
// 13.000 us; speedup vs baseline: 2.2490x; 1.2398x over previous
//
#include <hip/hip_runtime.h>

#define BB 64
#define KK 128
#define DD 128
#define HH 64

typedef __attribute__((ext_vector_type(8))) short bf16x8;
typedef __attribute__((ext_vector_type(4))) float f32x4;
typedef _Float16 half2v __attribute__((ext_vector_type(2)));
typedef __fp16 fp16x2 __attribute__((ext_vector_type(2)));

__device__ __forceinline__ unsigned cvt_pk_bf16(float x, float y) {
    unsigned r;
    asm("v_cvt_pk_bf16_f32 %0, %1, %2" : "=v"(r) : "v"(x), "v"(y));
    return r;
}

// packed f16 pair from two f32 (round-toward-zero pack)
__device__ __forceinline__ unsigned cvt_pkrtz_u(float x, float y) {
    const fp16x2 pk = __builtin_amdgcn_cvt_pkrtz(x, y);
    return __builtin_bit_cast(unsigned, pk);
}

// relu(a+b) on packed f16 pairs
__device__ __forceinline__ unsigned pk_add_relu(unsigned a, unsigned b) {
    unsigned s, r;
    asm("v_pk_add_f16 %0, %1, %2" : "=v"(s) : "v"(a), "v"(b));
    asm("v_pk_max_f16 %0, %1, 0" : "=v"(r) : "v"(s));
    return r;
}

__device__ __forceinline__ float dot2acc(unsigned a, unsigned b, float c) {
#if __has_builtin(__builtin_amdgcn_fdot2)
    return __builtin_amdgcn_fdot2(__builtin_bit_cast(half2v, a),
                                  __builtin_bit_cast(half2v, b), c, false);
#else
    float r;
    asm("v_dot2_f32_f16 %0, %1, %2, %3" : "=v"(r) : "v"(a), "v"(b), "v"(c));
    return r;
#endif
}

// LDS map (64 KiB union, barrier-separated):
//  phase A: SA  bf16[128][128] @ 0      (rows 0-63: slots i-tile, 64-127: j-tile)
//           W1s bf16[64][256]  @ 32768
//           both XOR-swizzled per 16B block: blk' = blk ^ (row & 7)
//  phase B: LsP half2[64][36] @ 0, RsP half2[64][36] @ 9216 (word 2304),
//           W2p half2[32] @ 18432 (word 4608)
//           half2 col c holds h-pair (32*(c>>4)+(c&15), +16)
__global__ __launch_bounds__(256) void fused_kernel(
    const float* __restrict__ slots, const float* __restrict__ W1,
    const float* __restrict__ b1, const float* __restrict__ W2,
    const float* __restrict__ b2p, float* __restrict__ out)
{
    __shared__ unsigned smem_w[16384];           // 65536 B
    char* smem = (char*)smem_w;

    const int t   = threadIdx.x;
    const int blk = blockIdx.x;
    const int b   = blk >> 2;
    const int it  = (blk >> 1) & 1;
    const int jt  = blk & 1;

    const int lane = t & 63;
    const int w    = t >> 6;
    const int lr   = lane & 15;
    const int lk   = lane >> 4;
    const int side = w >> 1;                     // 0: L-GEMM, 1: R-GEMM
    const int grp  = w & 1;                      // h-group (h in [32*grp, 32*grp+32))

    // early uniform-ish loads
    const float b1lo = (side == 0) ? b1[grp * 32 + lr]      : 0.0f;
    const float b1hi = (side == 0) ? b1[grp * 32 + 16 + lr] : 0.0f;
    float w2lo = 0.f, w2hi = 0.f;
    if (t < 32) {
        const int hl = (t & 15) + 32 * (t >> 4);
        w2lo = W2[hl]; w2hi = W2[hl + 16];
    }

    // ---------------- stage SA + W1 as swizzled bf16 ----------------
    {
        const float* srcI = slots + ((size_t)(b * KK) + it * 64) * DD;
        const float* srcJ = slots + ((size_t)(b * KK) + jt * 64) * DD;
#pragma unroll
        for (int x0 = 0; x0 < 2048; x0 += 256) {           // 128 rows x 16 16B-blocks
            const int x = x0 + t;
            const int row = x >> 4, cb = x & 15;
            const float* src = (row < 64 ? srcI + row * DD
                                         : srcJ + (row - 64) * DD) + cb * 8;
            const float4 f0 = *reinterpret_cast<const float4*>(src);
            const float4 f1 = *reinterpret_cast<const float4*>(src + 4);
            uint4 pk;
            pk.x = cvt_pk_bf16(f0.x, f0.y); pk.y = cvt_pk_bf16(f0.z, f0.w);
            pk.z = cvt_pk_bf16(f1.x, f1.y); pk.w = cvt_pk_bf16(f1.z, f1.w);
            *reinterpret_cast<uint4*>(smem + row * 256 + ((cb ^ (row & 7)) << 4)) = pk;
        }
#pragma unroll
        for (int x0 = 0; x0 < 2048; x0 += 256) {           // 64 rows x 32 16B-blocks
            const int x = x0 + t;
            const int row = x >> 5, cb = x & 31;
            const float* src = W1 + row * 256 + cb * 8;
            const float4 f0 = *reinterpret_cast<const float4*>(src);
            const float4 f1 = *reinterpret_cast<const float4*>(src + 4);
            uint4 pk;
            pk.x = cvt_pk_bf16(f0.x, f0.y); pk.y = cvt_pk_bf16(f0.z, f0.w);
            pk.z = cvt_pk_bf16(f1.x, f1.y); pk.w = cvt_pk_bf16(f1.z, f1.w);
            *reinterpret_cast<uint4*>(smem + 32768 + row * 512 + ((cb ^ (row & 7)) << 4)) = pk;
        }
    }
    __syncthreads();

    // ---------------- MFMA (wave-specialized): side x h-group ----------------
    // wave computes (L or R)[all 64 rows][32 h] ; A rows = side*64.., B rows = grp*32..
    bf16x8 af[4][4];
#pragma unroll
    for (int m = 0; m < 4; ++m)
#pragma unroll
        for (int kf = 0; kf < 4; ++kf) {
            const int row = side * 64 + 16 * m + lr;
            const int cb  = kf * 4 + lk;
            af[m][kf] = *reinterpret_cast<const bf16x8*>(
                smem + row * 256 + ((cb ^ (row & 7)) << 4));
        }
    bf16x8 bfr[2][4];
#pragma unroll
    for (int n = 0; n < 2; ++n)
#pragma unroll
        for (int kf = 0; kf < 4; ++kf) {
            const int rowB = grp * 32 + n * 16 + lr;
            const int cb   = side * 16 + kf * 4 + lk;
            bfr[n][kf] = *reinterpret_cast<const bf16x8*>(
                smem + 32768 + rowB * 512 + ((cb ^ (rowB & 7)) << 4));
        }

    f32x4 acc[4][2];
#pragma unroll
    for (int m = 0; m < 4; ++m)
#pragma unroll
        for (int n = 0; n < 2; ++n) acc[m][n] = f32x4{0.f, 0.f, 0.f, 0.f};
#pragma unroll
    for (int m = 0; m < 4; ++m)
#pragma unroll
        for (int n = 0; n < 2; ++n)
#pragma unroll
            for (int kf = 0; kf < 4; ++kf)
                acc[m][n] = __builtin_amdgcn_mfma_f32_16x16x32_bf16(
                    af[m][kf], bfr[n][kf], acc[m][n], 0, 0, 0);
    __syncthreads();

    // ---------------- spill as packed half2 (h, h+16) pairs ----------------
    {
        unsigned* dst = (unsigned*)smem + (side ? 2304 : 0);   // LsP / RsP words
#pragma unroll
        for (int m = 0; m < 4; ++m)
#pragma unroll
            for (int r = 0; r < 4; ++r) {
                const int row = 16 * m + 4 * lk + r;           // D: row = 4*(lane>>4)+reg
                dst[row * 36 + grp * 16 + lr] =
                    cvt_pkrtz_u(acc[m][0][r] + b1lo, acc[m][1][r] + b1hi);
            }
        if (t < 32) {
            ((unsigned*)smem)[4608 + t] = cvt_pkrtz_u(w2lo, w2hi);
        }
    }
    __syncthreads();

    // ---------------- pairwise: sigmoid(b2 + sum relu(L+R)*W2) ----------------
    const int tx = t & 15;                  // j = tx + 16*jj
    const int ty = t >> 4;                  // i = ty + 16*ii
    const unsigned* LsP = (const unsigned*)smem;
    const unsigned* RsP = LsP + 2304;
    const unsigned* W2p = LsP + 4608;

    uint4 w2r[8];
#pragma unroll
    for (int s = 0; s < 8; ++s)
        w2r[s] = *reinterpret_cast<const uint4*>(W2p + s * 4);

    float pacc[4][4] = {};
#pragma unroll
    for (int s = 0; s < 8; ++s) {
        uint4 l4[4], r4[4];
#pragma unroll
        for (int ii = 0; ii < 4; ++ii)
            l4[ii] = *reinterpret_cast<const uint4*>(LsP + (ty + 16 * ii) * 36 + s * 4);
#pragma unroll
        for (int jj = 0; jj < 4; ++jj)
            r4[jj] = *reinterpret_cast<const uint4*>(RsP + (tx + 16 * jj) * 36 + s * 4);
#pragma unroll
        for (int ii = 0; ii < 4; ++ii)
#pragma unroll
            for (int jj = 0; jj < 4; ++jj) {
                float a = pacc[ii][jj];
                a = dot2acc(pk_add_relu(l4[ii].x, r4[jj].x), w2r[s].x, a);
                a = dot2acc(pk_add_relu(l4[ii].y, r4[jj].y), w2r[s].y, a);
                a = dot2acc(pk_add_relu(l4[ii].z, r4[jj].z), w2r[s].z, a);
                a = dot2acc(pk_add_relu(l4[ii].w, r4[jj].w), w2r[s].w, a);
                pacc[ii][jj] = a;
            }
    }

    const float b2 = *b2p;
#pragma unroll
    for (int ii = 0; ii < 4; ++ii) {
        const int gi = it * 64 + ty + 16 * ii;
        float* orow = out + ((size_t)(b * KK) + gi) * KK + jt * 64;
#pragma unroll
        for (int jj = 0; jj < 4; ++jj) {
            const int jl = tx + 16 * jj;
            const int gj = jt * 64 + jl;
            const float xv = pacc[ii][jj] + b2;
            const float sg = 1.0f / (1.0f + __expf(-xv));
            orow[jl] = (gi == gj) ? 0.0f : sg;
        }
    }
}

extern "C" void kernel_launch(void* const* d_in, const int* in_sizes, int n_in,
                              void* d_out, int out_size, void* d_ws, size_t ws_size,
                              hipStream_t stream) {
    const float* slots = (const float*)d_in[0];
    const float* W1    = (const float*)d_in[1];
    const float* b1    = (const float*)d_in[2];
    const float* W2    = (const float*)d_in[3];
    const float* b2    = (const float*)d_in[4];
    float* out = (float*)d_out;
    (void)d_ws; (void)ws_size; (void)in_sizes; (void)n_in; (void)out_size;

    fused_kernel<<<BB * 4, 256, 0, stream>>>(slots, W1, b1, W2, b2, out);
}

// Round 5
// 12.561 us; speedup vs baseline: 2.3275x; 1.0349x over previous
//
#include <hip/hip_runtime.h>

#define BB 64
#define KK 128
#define DD 128

typedef __attribute__((ext_vector_type(8))) short bf16x8;
typedef __attribute__((ext_vector_type(4))) float f32x4;
typedef _Float16 half2v __attribute__((ext_vector_type(2)));
typedef __fp16 fp16x2 __attribute__((ext_vector_type(2)));

__device__ __forceinline__ unsigned cvt_pk_bf16(float x, float y) {
    unsigned r;
    asm("v_cvt_pk_bf16_f32 %0, %1, %2" : "=v"(r) : "v"(x), "v"(y));
    return r;
}

__device__ __forceinline__ unsigned cvt_pkrtz_u(float x, float y) {
    const fp16x2 pk = __builtin_amdgcn_cvt_pkrtz(x, y);
    return __builtin_bit_cast(unsigned, pk);
}

// relu(a+b) on packed f16 pairs
__device__ __forceinline__ unsigned pk_add_relu(unsigned a, unsigned b) {
    unsigned s, r;
    asm("v_pk_add_f16 %0, %1, %2" : "=v"(s) : "v"(a), "v"(b));
    asm("v_pk_max_f16 %0, %1, 0" : "=v"(r) : "v"(s));
    return r;
}

__device__ __forceinline__ float dot2acc(unsigned a, unsigned b, float c) {
#if __has_builtin(__builtin_amdgcn_fdot2)
    return __builtin_amdgcn_fdot2(__builtin_bit_cast(half2v, a),
                                  __builtin_bit_cast(half2v, b), c, false);
#else
    float r;
    asm("v_dot2_f32_f16 %0, %1, %2, %3" : "=v"(r) : "v"(a), "v"(b), "v"(c));
    return r;
#endif
}

// Block = 512 threads (8 waves, 2/SIMD), grid = 256 (1 block/CU, zero redundancy).
// LDS map (64 KiB union, barrier-separated):
//  phase A: SA  bf16[128][128] @ 0      (rows 0-63: slots i-tile, 64-127: j-tile)
//           W1s bf16[64][256]  @ 32768
//           both XOR-swizzled per 16B block: blk' = blk ^ (row & 7)
//  phase B: LsP half2[64][36] @ word 0, RsP half2[64][36] @ word 2304,
//           W2p half2[32] @ word 4608
//           half2 word c holds h-pair (32*(c>>4)+(c&15), +16)
// MFMA specialization: wave w -> side = w>>2 (L/R), hq = w&3 (16-wide h slice).
__global__ __launch_bounds__(512, 2) void fused_kernel(
    const float* __restrict__ slots, const float* __restrict__ W1,
    const float* __restrict__ b1, const float* __restrict__ W2,
    const float* __restrict__ b2p, float* __restrict__ out)
{
    __shared__ unsigned smem_w[16384];           // 65536 B
    char* smem = (char*)smem_w;

    const int t   = threadIdx.x;
    const int blk = blockIdx.x;
    const int b   = blk >> 2;
    const int it  = (blk >> 1) & 1;
    const int jt  = blk & 1;

    const int lane = t & 63;
    const int w    = t >> 6;                     // 0..7
    const int lr   = lane & 15;
    const int lk   = lane >> 4;
    const int side = w >> 2;                     // 0: L-GEMM, 1: R-GEMM
    const int hq   = w & 3;                      // h slice [16*hq, 16*hq+16)

    const float badd = (side == 0) ? b1[hq * 16 + lr] : 0.0f;
    float w2lo = 0.f, w2hi = 0.f;
    if (t < 32) {
        const int hl = (t & 15) + 32 * (t >> 4);
        w2lo = W2[hl]; w2hi = W2[hl + 16];
    }

    // ---------------- stage SA + W1 as swizzled bf16 ----------------
    {
        const float* srcI = slots + ((size_t)(b * KK) + it * 64) * DD;
        const float* srcJ = slots + ((size_t)(b * KK) + jt * 64) * DD;
#pragma unroll
        for (int x0 = 0; x0 < 2048; x0 += 512) {           // 128 rows x 16 16B-blocks
            const int x = x0 + t;
            const int row = x >> 4, cb = x & 15;
            const float* src = (row < 64 ? srcI + row * DD
                                         : srcJ + (row - 64) * DD) + cb * 8;
            const float4 f0 = *reinterpret_cast<const float4*>(src);
            const float4 f1 = *reinterpret_cast<const float4*>(src + 4);
            uint4 pk;
            pk.x = cvt_pk_bf16(f0.x, f0.y); pk.y = cvt_pk_bf16(f0.z, f0.w);
            pk.z = cvt_pk_bf16(f1.x, f1.y); pk.w = cvt_pk_bf16(f1.z, f1.w);
            *reinterpret_cast<uint4*>(smem + row * 256 + ((cb ^ (row & 7)) << 4)) = pk;
        }
#pragma unroll
        for (int x0 = 0; x0 < 2048; x0 += 512) {           // 64 rows x 32 16B-blocks
            const int x = x0 + t;
            const int row = x >> 5, cb = x & 31;
            const float* src = W1 + row * 256 + cb * 8;
            const float4 f0 = *reinterpret_cast<const float4*>(src);
            const float4 f1 = *reinterpret_cast<const float4*>(src + 4);
            uint4 pk;
            pk.x = cvt_pk_bf16(f0.x, f0.y); pk.y = cvt_pk_bf16(f0.z, f0.w);
            pk.z = cvt_pk_bf16(f1.x, f1.y); pk.w = cvt_pk_bf16(f1.z, f1.w);
            *reinterpret_cast<uint4*>(smem + 32768 + row * 512 + ((cb ^ (row & 7)) << 4)) = pk;
        }
    }
    __syncthreads();

    // ---------------- MFMA: wave = side x h-quarter ----------------
    bf16x8 bfr[4];
#pragma unroll
    for (int kf = 0; kf < 4; ++kf) {
        const int rowB = hq * 16 + lr;
        const int cb   = side * 16 + kf * 4 + lk;
        bfr[kf] = *reinterpret_cast<const bf16x8*>(
            smem + 32768 + rowB * 512 + ((cb ^ (rowB & 7)) << 4));
    }
    f32x4 acc[4];
#pragma unroll
    for (int m = 0; m < 4; ++m) acc[m] = f32x4{0.f, 0.f, 0.f, 0.f};
#pragma unroll
    for (int m = 0; m < 4; ++m) {
#pragma unroll
        for (int kf = 0; kf < 4; ++kf) {
            const int row = side * 64 + 16 * m + lr;
            const int cb  = kf * 4 + lk;
            const bf16x8 af = *reinterpret_cast<const bf16x8*>(
                smem + row * 256 + ((cb ^ (row & 7)) << 4));
            acc[m] = __builtin_amdgcn_mfma_f32_16x16x32_bf16(af, bfr[kf], acc[m], 0, 0, 0);
        }
    }
    __syncthreads();

    // ---------------- spill as f16 halves into (h, h+16) word layout ----------------
    {
        __fp16* dst = (__fp16*)smem + (side ? 4608 : 0);   // L words 0.., R words 2304..
        const int g  = hq >> 1;
        const int hl = hq & 1;
#pragma unroll
        for (int m = 0; m < 4; ++m)
#pragma unroll
            for (int r = 0; r < 4; ++r) {
                const int row = 16 * m + 4 * lk + r;       // D: row = 4*(lane>>4)+reg
                dst[(row * 36 + g * 16 + lr) * 2 + hl] = (__fp16)(acc[m][r] + badd);
            }
        if (t < 32) ((unsigned*)smem)[4608 + t] = cvt_pkrtz_u(w2lo, w2hi);
    }
    __syncthreads();

    // ---------------- pairwise: sigmoid(b2 + sum relu(L+R)*W2) ----------------
    const int tx = t & 15;                  // j = tx + 16*jj
    const int ty = t >> 4;                  // i = ty + 32*ii  (ty 0..31)
    const unsigned* LsP = (const unsigned*)smem;
    const unsigned* RsP = LsP + 2304;
    const unsigned* W2p = LsP + 4608;

    uint4 w2r[8];
#pragma unroll
    for (int s = 0; s < 8; ++s)
        w2r[s] = *reinterpret_cast<const uint4*>(W2p + s * 4);

    float pacc[2][4] = {};
    uint4 l4a[2], r4a[4], l4b[2], r4b[4];

#define LD_STEP(L4, R4, s)                                                        \
    {                                                                             \
        _Pragma("unroll") for (int ii = 0; ii < 2; ++ii)                          \
            L4[ii] = *reinterpret_cast<const uint4*>(LsP + (ty + 32 * ii) * 36 + (s) * 4); \
        _Pragma("unroll") for (int jj = 0; jj < 4; ++jj)                          \
            R4[jj] = *reinterpret_cast<const uint4*>(RsP + (tx + 16 * jj) * 36 + (s) * 4); \
    }

#define COMPUTE_STEP(L4, R4, s)                                                   \
    {                                                                             \
        _Pragma("unroll") for (int ii = 0; ii < 2; ++ii)                          \
        _Pragma("unroll") for (int jj = 0; jj < 4; ++jj) {                        \
            float a = pacc[ii][jj];                                               \
            a = dot2acc(pk_add_relu(L4[ii].x, R4[jj].x), w2r[s].x, a);            \
            a = dot2acc(pk_add_relu(L4[ii].y, R4[jj].y), w2r[s].y, a);            \
            a = dot2acc(pk_add_relu(L4[ii].z, R4[jj].z), w2r[s].z, a);            \
            a = dot2acc(pk_add_relu(L4[ii].w, R4[jj].w), w2r[s].w, a);            \
            pacc[ii][jj] = a;                                                     \
        }                                                                         \
    }

    LD_STEP(l4a, r4a, 0)
#pragma unroll
    for (int sp = 0; sp < 4; ++sp) {
        LD_STEP(l4b, r4b, 2 * sp + 1)
        COMPUTE_STEP(l4a, r4a, 2 * sp)
        if (sp < 3) LD_STEP(l4a, r4a, 2 * sp + 2)
        COMPUTE_STEP(l4b, r4b, 2 * sp + 1)
    }
#undef LD_STEP
#undef COMPUTE_STEP

    const float b2 = *b2p;
#pragma unroll
    for (int ii = 0; ii < 2; ++ii) {
        const int gi = it * 64 + ty + 32 * ii;
        float* orow = out + ((size_t)(b * KK) + gi) * KK + jt * 64;
#pragma unroll
        for (int jj = 0; jj < 4; ++jj) {
            const int jl = tx + 16 * jj;
            const int gj = jt * 64 + jl;
            const float xv = pacc[ii][jj] + b2;
            const float sg = 1.0f / (1.0f + __expf(-xv));
            orow[jl] = (gi == gj) ? 0.0f : sg;
        }
    }
}

extern "C" void kernel_launch(void* const* d_in, const int* in_sizes, int n_in,
                              void* d_out, int out_size, void* d_ws, size_t ws_size,
                              hipStream_t stream) {
    const float* slots = (const float*)d_in[0];
    const float* W1    = (const float*)d_in[1];
    const float* b1    = (const float*)d_in[2];
    const float* W2    = (const float*)d_in[3];
    const float* b2    = (const float*)d_in[4];
    float* out = (float*)d_out;
    (void)d_ws; (void)ws_size; (void)in_sizes; (void)n_in; (void)out_size;

    fused_kernel<<<BB * 4, 512, 0, stream>>>(slots, W1, b1, W2, b2, out);
}